// Round 19
// baseline (465.975 us; speedup 1.0000x reference)
//
#include <hip/hip_runtime.h>
#include <hip/hip_bf16.h>
#include <stdint.h>

#define BATCH 512
#define TSTEPS 64
#define DIN 1024
#define HID 512
#define G3 1536
#define MROWS (BATCH * TSTEPS)
#define POUT 512

typedef __attribute__((ext_vector_type(8))) short bf16x8;
typedef __attribute__((ext_vector_type(4))) float f32x4;

__device__ __forceinline__ float bf2f(short s) {
  union { unsigned u; float f; } v;
  v.u = ((unsigned)(unsigned short)s) << 16;
  return v.f;
}
__device__ __forceinline__ short f2bf(float f) {
  __hip_bfloat16 h = __float2bfloat16(f);
  short s;
  __builtin_memcpy(&s, &h, 2);
  return s;
}
__device__ __forceinline__ void gload_lds16(const void* g, void* l) {
  __builtin_amdgcn_global_load_lds(
      (const __attribute__((address_space(1))) void*)g,
      (__attribute__((address_space(3))) void*)l, 16, 0, 0);
}

// ---------------------------------------------------------------------------
// X fp32 -> bf16 precast (row order preserved): enables global_load_lds A.
// ---------------------------------------------------------------------------
__global__ __launch_bounds__(256) void xcast(const float* __restrict__ in,
                                             short* __restrict__ out) {
  const size_t i = ((size_t)blockIdx.x * 256 + threadIdx.x) * 8;
  const float4 a = *reinterpret_cast<const float4*>(in + i);
  const float4 b = *reinterpret_cast<const float4*>(in + i + 4);
  bf16x8 v;
  v[0] = f2bf(a.x); v[1] = f2bf(a.y); v[2] = f2bf(a.z); v[3] = f2bf(a.w);
  v[4] = f2bf(b.x); v[5] = f2bf(b.y); v[6] = f2bf(b.z); v[7] = f2bf(b.w);
  *reinterpret_cast<bf16x8*>(out + i) = v;
}

// ---------------------------------------------------------------------------
// transpose + fp32->bf16 cast: out[c][r] = bf16(in[r][c])  (for W_in -> Wt)
// ---------------------------------------------------------------------------
__global__ __launch_bounds__(256) void transpose_cast(const float* __restrict__ in,
                                                      short* __restrict__ out,
                                                      int R, int C) {
  __shared__ float tile[32][33];
  const int c0 = blockIdx.x * 32, r0 = blockIdx.y * 32;
  const int tx = threadIdx.x & 31, ty = threadIdx.x >> 5;
#pragma unroll
  for (int i = 0; i < 4; ++i) {
    const int r = r0 + ty + i * 8;
    tile[ty + i * 8][tx] = in[(size_t)r * C + c0 + tx];
  }
  __syncthreads();
#pragma unroll
  for (int i = 0; i < 4; ++i) {
    const int c = c0 + ty + i * 8;
    out[(size_t)c * R + r0 + tx] = f2bf(tile[tx][ty + i * 8]);
  }
}

// ---------------------------------------------------------------------------
// Pack U (fp32 [512][1536]) -> Upk2 bf16 [cg8][f48][wn4][lg4][lc16][e8]
// (B-fragments for the scan's register-resident U).
// ---------------------------------------------------------------------------
__global__ __launch_bounds__(256) void u_pack2(const float* __restrict__ U,
                                               short* __restrict__ Upk2) {
  const unsigned idx = blockIdx.x * 256 + threadIdx.x;  // < 786432
  const unsigned e = idx & 7u;
  unsigned tmp = idx >> 3;
  const unsigned lc = tmp & 15u; tmp >>= 4;
  const unsigned lg = tmp & 3u;  tmp >>= 2;
  const unsigned wn = tmp & 3u;  tmp >>= 2;  // tmp = cg*48 + f
  const unsigned f = tmp % 48u;
  const unsigned cg = tmp / 48u;
  const unsigned g = f >> 4, kc = f & 15u;
  const unsigned k = kc * 32u + lg * 8u + e;
  const unsigned col = g * 512u + cg * 64u + wn * 16u + lc;
  Upk2[idx] = f2bf(U[(size_t)k * G3 + col]);
}

// ---------------------------------------------------------------------------
// Kernel 1: XG = bf16(Xbf @ W_in + b_in), MFMA 128x128 BK=64.
// BOTH operands via global_load_lds (pre-swizzled sources, linear LDS dest).
// Output layout: XG[t][bg16][cg8][bl32][g3][cc64]. Per-XCD tile chunks.
// ---------------------------------------------------------------------------
__global__ __launch_bounds__(256) void gemm_xg_mfma(const short* __restrict__ Xbf,
                                                    const short* __restrict__ Wt,
                                                    const float* __restrict__ bin,
                                                    __hip_bfloat16* __restrict__ XG) {
  __shared__ __align__(16) short As[128 * 64];
  __shared__ __align__(16) short Bs[128 * 64];
  const int tid = threadIdx.x;
  const int w = tid >> 6, l = tid & 63;
  const int lc = l & 15, lg = l >> 4;

  const int xcd = blockIdx.x & 7;
  const int idx = blockIdx.x >> 3;          // 0..383
  const int wg = xcd * 384 + idx;           // contiguous chunk per XCD
  const int rt = wg / 12, ct = wg % 12;     // 12 consecutive share row-panel
  const int row0 = rt * 128, col0 = ct * 128;

  const int wm = w >> 1, wn = w & 1;

  f32x4 acc[4][4];
#pragma unroll
  for (int mt = 0; mt < 4; ++mt)
#pragma unroll
    for (int nt = 0; nt < 4; ++nt) acc[mt][nt] = (f32x4){0.f, 0.f, 0.f, 0.f};

  for (int k0 = 0; k0 < DIN; k0 += 64) {
    __syncthreads();  // prev MFMAs done reading LDS
#pragma unroll
    for (int i = 0; i < 4; ++i) {
      const int rr = w * 32 + i * 8 + (l >> 3);
      const int s = (l & 7) ^ (rr & 7);
      gload_lds16(&Xbf[(size_t)(row0 + rr) * DIN + k0 + s * 8],
                  (char*)As + (w * 32 + i * 8) * 128);
      gload_lds16(&Wt[(size_t)(col0 + rr) * DIN + k0 + s * 8],
                  (char*)Bs + (w * 32 + i * 8) * 128);
    }
    __syncthreads();  // staging visible
#pragma unroll
    for (int kc = 0; kc < 2; ++kc) {
      bf16x8 a[4], b[4];
#pragma unroll
      for (int mt = 0; mt < 4; ++mt) {
        const int R = wm * 64 + mt * 16 + lc;
        const int ch = (kc * 4 + lg) ^ (R & 7);
        a[mt] = *reinterpret_cast<const bf16x8*>((const char*)As + R * 128 + ch * 16);
      }
#pragma unroll
      for (int nt = 0; nt < 4; ++nt) {
        const int Rn = wn * 64 + nt * 16 + lc;
        const int ch = (kc * 4 + lg) ^ (Rn & 7);
        b[nt] = *reinterpret_cast<const bf16x8*>((const char*)Bs + Rn * 128 + ch * 16);
      }
#pragma unroll
      for (int mt = 0; mt < 4; ++mt)
#pragma unroll
        for (int nt = 0; nt < 4; ++nt)
          acc[mt][nt] = __builtin_amdgcn_mfma_f32_16x16x32_bf16(a[mt], b[nt],
                                                                acc[mt][nt], 0, 0, 0);
    }
  }

  float bv[4];
#pragma unroll
  for (int nt = 0; nt < 4; ++nt) bv[nt] = bin[col0 + wn * 64 + nt * 16 + lc];
#pragma unroll
  for (int mt = 0; mt < 4; ++mt) {
#pragma unroll
    for (int nt = 0; nt < 4; ++nt) {
      const int col = col0 + wn * 64 + nt * 16 + lc;
      const int g = col >> 9;
      const int rem = col & 511;
      const int cgc = rem >> 6, cc = rem & 63;
#pragma unroll
      for (int rr = 0; rr < 4; ++rr) {
        const int m = row0 + wm * 64 + mt * 16 + lg * 4 + rr;
        const int t = m & 63, b = m >> 6;
        const size_t o =
            ((((size_t)t * 16 + (b >> 5)) * 8 + cgc) * 32 + (b & 31)) * 192 +
            g * 64 + cc;
        XG[o] = __float2bfloat16(acc[mt][nt][rr] + bv[nt]);
      }
    }
  }
}

// ---------------------------------------------------------------------------
// Kernel 2: persistent cooperative GRU scan (R15 protocol), U pinned in
// VGPRs. amdgpu_waves_per_eu(2,2) fixes exactly 2 waves/EU (the block's
// structural occupancy anyway) so the allocator may use up to 256 VGPRs --
// R18's null showed launch_bounds alone leaves the 128-VGPR heuristic in
// place and U re-streams 384 KB/block/step from L2 (~1.4 us of the step).
// ---------------------------------------------------------------------------
__global__ __launch_bounds__(512, 2)
__attribute__((amdgpu_waves_per_eu(2, 2))) void gru_scan_coop(
    const __hip_bfloat16* __restrict__ XG, const short* __restrict__ Upk2,
    const float* __restrict__ brec, short* h_g, unsigned* bar,
    float* __restrict__ HT) {
  __shared__ __align__(16) short hS[32 * 512];   // 32 KB (swizzled image)
  __shared__ __align__(16) short xgL[2][6144];   // 24 KB
  const int tid = threadIdx.x, w = tid >> 6, l = tid & 63;
  const int lc = l & 15, lg = l >> 4;
  const int bg = blockIdx.x >> 3, cgi = blockIdx.x & 7;
  const int b0 = bg * 32, c0 = cgi * 64;
  const int wm = w & 1, wn = w >> 1;  // 2 batch-tiles x 4 col-tiles
  unsigned* const flags = bar + bg * 16;

  // ---- U fragments -> VGPRs, PINNED (one-time load, register-resident) ----
  bf16x8 ub[3][16];
#pragma unroll
  for (int g = 0; g < 3; ++g)
#pragma unroll
    for (int kc = 0; kc < 16; ++kc)
      ub[g][kc] = *reinterpret_cast<const bf16x8*>(
          Upk2 + ((((size_t)cgi * 48 + g * 16 + kc) * 4 + wn) * 4 + lg) * 128 +
          lc * 8);
#pragma unroll
  for (int g = 0; g < 3; ++g)
#pragma unroll
    for (int kc = 0; kc < 16; ++kc)
      asm volatile("" : "+v"(ub[g][kc]));  // opaque def: no rematerialization

  // zero hS: t=0 computes with h=0 (gates read hold from hS at t=0)
  for (int i = tid; i < 4096; i += 512) ((unsigned long long*)hS)[i] = 0ull;

  const short* XGs = (const short*)XG;
  {  // stage xg(t=0): 12KB slice = 768 chunks (512 + 256), linear
    const short* xs = XGs + ((size_t)bg * 8 + cgi) * 6144;
    gload_lds16(xs + tid * 8, (char*)xgL[0] + w * 1024);
    if (tid < 256)
      gload_lds16(xs + (512 + tid) * 8, (char*)xgL[0] + 8192 + w * 1024);
  }

  const int j = c0 + wn * 16 + lc;  // this lane's h/gate column
  const float brz = brec[j], brr = brec[512 + j], brh = brec[1024 + j];
  const int arow = wm * 16 + lc;

  __syncthreads();  // hS + xg(0) ready (compiler drains vmcnt)

  for (int t = 0; t < TSTEPS; ++t) {
    f32x4 za0 = (f32x4){0.f, 0.f, 0.f, 0.f}, za1 = za0, za2 = za0;
    if (t > 0) {
      // ---- wait for all 8 producers of h(t) ----
      for (;;) {
        const unsigned f = __hip_atomic_load(&flags[l & 7], __ATOMIC_RELAXED,
                                             __HIP_MEMORY_SCOPE_AGENT);
        if (__all((int)(f >= (unsigned)t))) break;
        __builtin_amdgcn_s_sleep(1);
      }
      // ---- coalesced h loads (relaxed agent atomics, swizzled image) ----
      const unsigned long long* hsrc = (const unsigned long long*)(
          h_g + ((size_t)(t & 1) * BATCH + b0) * 512);
      unsigned long long v[8];
#pragma unroll
      for (int r = 0; r < 8; ++r)
        v[r] = __hip_atomic_load(hsrc + r * 512 + tid, __ATOMIC_RELAXED,
                                 __HIP_MEMORY_SCOPE_AGENT);
#pragma unroll
      for (int r = 0; r < 8; ++r)
        ((unsigned long long*)hS)[r * 512 + tid] = v[r];
      __syncthreads();  // hS ready

      // ---- hg = h @ U : 48 MFMAs, A from swizzled hS, B from VGPRs ----
#pragma unroll
      for (int kc = 0; kc < 16; ++kc) {
        const int s = kc * 4 + lg;
        const bf16x8 a = *(const bf16x8*)((const char*)hS + arow * 1024 +
                                          ((s ^ (arow & 7)) << 4));
        za0 = __builtin_amdgcn_mfma_f32_16x16x32_bf16(a, ub[0][kc], za0, 0, 0, 0);
        za1 = __builtin_amdgcn_mfma_f32_16x16x32_bf16(a, ub[1][kc], za1, 0, 0, 0);
        za2 = __builtin_amdgcn_mfma_f32_16x16x32_bf16(a, ub[2][kc], za2, 0, 0, 0);
      }
    }

    // ---- gates in-register; C/D: col=lane&15, row=(lane>>4)*4+reg ----
    const short* xb = xgL[t & 1];
#pragma unroll
    for (int r = 0; r < 4; ++r) {
      const int lb = wm * 16 + lg * 4 + r;
      const float xz = bf2f(xb[lb * 192 + wn * 16 + lc]);
      const float xr = bf2f(xb[lb * 192 + 64 + wn * 16 + lc]);
      const float xh = bf2f(xb[lb * 192 + 128 + wn * 16 + lc]);
      const float z = 1.f / (1.f + __expf(-(xz + za0[r] + brz)));
      const float rg = 1.f / (1.f + __expf(-(xr + za1[r] + brr)));
      const float hc = fmaxf(fmaf(rg, za2[r] + brh, xh), 0.f);
      const int hoff = lb * 1024 + (((j >> 3) ^ (lb & 7)) << 4) + (j & 7) * 2;
      const float hold = bf2f(*(const short*)((const char*)hS + hoff));
      const float hnew = fmaf(z, hold - hc, hc);
      if (t == TSTEPS - 1) {
        HT[(size_t)(b0 + lb) * HID + j] = hnew;
      } else {
        __hip_atomic_store(
            (unsigned short*)((char*)h_g +
                              ((size_t)((t + 1) & 1) * BATCH + b0) * 1024 + hoff),
            (unsigned short)f2bf(hnew), __ATOMIC_RELAXED,
            __HIP_MEMORY_SCOPE_AGENT);
      }
    }
    if (t == TSTEPS - 1) break;

    __syncthreads();  // all waves' h stores drained (vmcnt 0 before barrier)
    if (tid == 0)
      __hip_atomic_store(&flags[cgi], (unsigned)(t + 1), __ATOMIC_RELAXED,
                         __HIP_MEMORY_SCOPE_AGENT);
    {  // stage xg(t+1) while flags propagate: 12KB slice (768 chunks)
      const short* xs = XGs + (((size_t)(t + 1) * 16 + bg) * 8 + cgi) * 6144;
      char* xd = (char*)xgL[(t + 1) & 1];
      gload_lds16(xs + tid * 8, xd + w * 1024);
      if (tid < 256)
        gload_lds16(xs + (512 + tid) * 8, xd + 8192 + w * 1024);
    }
  }
}

// ---------------------------------------------------------------------------
// Kernel 3: out = cat(hT,hT) @ W2 + b2 == hT @ (W2_top + W2_bot) + b2
// ---------------------------------------------------------------------------
__global__ __launch_bounds__(256) void final_proj(const float* __restrict__ HT,
                                                  const float* __restrict__ W2,
                                                  const float* __restrict__ b2,
                                                  float* __restrict__ OUT) {
  const int b = blockIdx.x >> 1;
  const int pp = ((blockIdx.x & 1) << 8) + threadIdx.x;
  float acc = b2[pp];
  const float* h = &HT[(size_t)b * HID];
  for (int k = 0; k < HID; ++k)
    acc = fmaf(h[k], W2[(size_t)k * POUT + pp] + W2[(size_t)(k + HID) * POUT + pp], acc);
  OUT[(size_t)b * POUT + pp] = acc;
}

// ---------------------------------------------------------------------------
extern "C" void kernel_launch(void* const* d_in, const int* in_sizes, int n_in,
                              void* d_out, int out_size, void* d_ws,
                              size_t ws_size, hipStream_t stream) {
  const float* X    = (const float*)d_in[0];
  const float* Win  = (const float*)d_in[1];
  const float* bin  = (const float*)d_in[2];
  const float* U    = (const float*)d_in[3];
  const float* brec = (const float*)d_in[4];
  const float* W2   = (const float*)d_in[5];
  const float* b2   = (const float*)d_in[6];
  float* OUT = (float*)d_out;

  char* ws = (char*)d_ws;
  size_t off = 0;
  __hip_bfloat16* XG = (__hip_bfloat16*)(ws + off); off += (size_t)MROWS * G3 * 2;  // 100.66 MB
  short* Wt   = (short*)(ws + off); off += (size_t)G3 * DIN * 2;                    // 3.15 MB
  short* Upk2 = (short*)(ws + off); off += (size_t)G3 * HID * 2;                    // 1.57 MB
  float* HT   = (float*)(ws + off); off += (size_t)BATCH * HID * 4;                 // 1.05 MB
  short* h_g  = (short*)(ws + off); off += (size_t)2 * BATCH * HID * 2;             // 1.05 MB (dbuf)
  unsigned* bar = (unsigned*)(ws + off); off += 4096;                               // flags
  short* Xbf  = (short*)(ws + off); off += (size_t)MROWS * DIN * 2;                 // 67.1 MB -> 174.7 MB total

  hipMemsetAsync(bar, 0, 1024, stream);  // flag slots; h_g needs no reset

  xcast<<<(MROWS * DIN) / (256 * 8), 256, 0, stream>>>(X, Xbf);
  transpose_cast<<<dim3(G3 / 32, DIN / 32), 256, 0, stream>>>(Win, Wt, DIN, G3);
  u_pack2<<<(HID * G3) / 256, 256, 0, stream>>>(U, Upk2);
  gemm_xg_mfma<<<(MROWS / 128) * (G3 / 128), 256, 0, stream>>>(Xbf, Wt, bin, XG);

  const __hip_bfloat16* XGc = XG;
  const short* Upkc = Upk2;
  void* args[] = {(void*)&XGc, (void*)&Upkc, (void*)&brec,
                  (void*)&h_g, (void*)&bar, (void*)&HT};
  hipLaunchCooperativeKernel((const void*)gru_scan_coop, dim3(128), dim3(512),
                             args, 0, stream);

  final_proj<<<(BATCH * POUT) / 256, 256, 0, stream>>>(HT, W2, b2, OUT);
}

// Round 20
// 430.093 us; speedup vs baseline: 1.0834x; 1.0834x over previous
//
#include <hip/hip_runtime.h>
#include <hip/hip_bf16.h>
#include <stdint.h>

#define BATCH 512
#define TSTEPS 64
#define DIN 1024
#define HID 512
#define G3 1536
#define MROWS (BATCH * TSTEPS)
#define POUT 512

typedef __attribute__((ext_vector_type(8))) short bf16x8;
typedef __attribute__((ext_vector_type(4))) float f32x4;

__device__ __forceinline__ float bf2f(short s) {
  union { unsigned u; float f; } v;
  v.u = ((unsigned)(unsigned short)s) << 16;
  return v.f;
}
__device__ __forceinline__ short f2bf(float f) {
  __hip_bfloat16 h = __float2bfloat16(f);
  short s;
  __builtin_memcpy(&s, &h, 2);
  return s;
}
__device__ __forceinline__ void gload_lds16(const void* g, void* l) {
  __builtin_amdgcn_global_load_lds(
      (const __attribute__((address_space(1))) void*)g,
      (__attribute__((address_space(3))) void*)l, 16, 0, 0);
}

// ---------------------------------------------------------------------------
// X fp32 -> bf16 precast (row order preserved): enables global_load_lds A.
// ---------------------------------------------------------------------------
__global__ __launch_bounds__(256) void xcast(const float* __restrict__ in,
                                             short* __restrict__ out) {
  const size_t i = ((size_t)blockIdx.x * 256 + threadIdx.x) * 8;
  const float4 a = *reinterpret_cast<const float4*>(in + i);
  const float4 b = *reinterpret_cast<const float4*>(in + i + 4);
  bf16x8 v;
  v[0] = f2bf(a.x); v[1] = f2bf(a.y); v[2] = f2bf(a.z); v[3] = f2bf(a.w);
  v[4] = f2bf(b.x); v[5] = f2bf(b.y); v[6] = f2bf(b.z); v[7] = f2bf(b.w);
  *reinterpret_cast<bf16x8*>(out + i) = v;
}

// ---------------------------------------------------------------------------
// transpose + fp32->bf16 cast: out[c][r] = bf16(in[r][c])  (for W_in -> Wt)
// ---------------------------------------------------------------------------
__global__ __launch_bounds__(256) void transpose_cast(const float* __restrict__ in,
                                                      short* __restrict__ out,
                                                      int R, int C) {
  __shared__ float tile[32][33];
  const int c0 = blockIdx.x * 32, r0 = blockIdx.y * 32;
  const int tx = threadIdx.x & 31, ty = threadIdx.x >> 5;
#pragma unroll
  for (int i = 0; i < 4; ++i) {
    const int r = r0 + ty + i * 8;
    tile[ty + i * 8][tx] = in[(size_t)r * C + c0 + tx];
  }
  __syncthreads();
#pragma unroll
  for (int i = 0; i < 4; ++i) {
    const int c = c0 + ty + i * 8;
    out[(size_t)c * R + r0 + tx] = f2bf(tile[tx][ty + i * 8]);
  }
}

// ---------------------------------------------------------------------------
// W2 pack: W2st[p][k] = bf16(W2[k][p] + W2[k+512][p]), p,k in [0,512).
// (cat(h,h) @ W2 == h @ (W2_top + W2_bot); transposed for gload B staging.)
// ---------------------------------------------------------------------------
__global__ __launch_bounds__(256) void w2_pack(const float* __restrict__ W2,
                                               short* __restrict__ W2st) {
  __shared__ float tile[32][33];
  const int c0 = blockIdx.x * 32, r0 = blockIdx.y * 32;  // c=p, r=k
  const int tx = threadIdx.x & 31, ty = threadIdx.x >> 5;
#pragma unroll
  for (int i = 0; i < 4; ++i) {
    const int r = r0 + ty + i * 8;
    tile[ty + i * 8][tx] = W2[(size_t)r * POUT + c0 + tx] +
                           W2[(size_t)(r + HID) * POUT + c0 + tx];
  }
  __syncthreads();
#pragma unroll
  for (int i = 0; i < 4; ++i) {
    const int c = c0 + ty + i * 8;
    W2st[(size_t)c * HID + r0 + tx] = f2bf(tile[tx][ty + i * 8]);
  }
}

// ---------------------------------------------------------------------------
// Pack U (fp32 [512][1536]) -> Upk2 bf16 [cg8][f48][wn4][lg4][lc16][e8]
// (B-fragments for the scan's U).
// ---------------------------------------------------------------------------
__global__ __launch_bounds__(256) void u_pack2(const float* __restrict__ U,
                                               short* __restrict__ Upk2) {
  const unsigned idx = blockIdx.x * 256 + threadIdx.x;  // < 786432
  const unsigned e = idx & 7u;
  unsigned tmp = idx >> 3;
  const unsigned lc = tmp & 15u; tmp >>= 4;
  const unsigned lg = tmp & 3u;  tmp >>= 2;
  const unsigned wn = tmp & 3u;  tmp >>= 2;  // tmp = cg*48 + f
  const unsigned f = tmp % 48u;
  const unsigned cg = tmp / 48u;
  const unsigned g = f >> 4, kc = f & 15u;
  const unsigned k = kc * 32u + lg * 8u + e;
  const unsigned col = g * 512u + cg * 64u + wn * 16u + lc;
  Upk2[idx] = f2bf(U[(size_t)k * G3 + col]);
}

// ---------------------------------------------------------------------------
// Kernel 1: XG = bf16(Xbf @ W_in + b_in), MFMA 128x128 BK=64.
// BOTH operands via global_load_lds (pre-swizzled sources, linear LDS dest).
// Output layout: XG[t][bg16][cg8][bl32][g3][cc64]. Per-XCD tile chunks.
// ---------------------------------------------------------------------------
__global__ __launch_bounds__(256) void gemm_xg_mfma(const short* __restrict__ Xbf,
                                                    const short* __restrict__ Wt,
                                                    const float* __restrict__ bin,
                                                    __hip_bfloat16* __restrict__ XG) {
  __shared__ __align__(16) short As[128 * 64];
  __shared__ __align__(16) short Bs[128 * 64];
  const int tid = threadIdx.x;
  const int w = tid >> 6, l = tid & 63;
  const int lc = l & 15, lg = l >> 4;

  const int xcd = blockIdx.x & 7;
  const int idx = blockIdx.x >> 3;          // 0..383
  const int wg = xcd * 384 + idx;           // contiguous chunk per XCD
  const int rt = wg / 12, ct = wg % 12;     // 12 consecutive share row-panel
  const int row0 = rt * 128, col0 = ct * 128;

  const int wm = w >> 1, wn = w & 1;

  f32x4 acc[4][4];
#pragma unroll
  for (int mt = 0; mt < 4; ++mt)
#pragma unroll
    for (int nt = 0; nt < 4; ++nt) acc[mt][nt] = (f32x4){0.f, 0.f, 0.f, 0.f};

  for (int k0 = 0; k0 < DIN; k0 += 64) {
    __syncthreads();  // prev MFMAs done reading LDS
#pragma unroll
    for (int i = 0; i < 4; ++i) {
      const int rr = w * 32 + i * 8 + (l >> 3);
      const int s = (l & 7) ^ (rr & 7);
      gload_lds16(&Xbf[(size_t)(row0 + rr) * DIN + k0 + s * 8],
                  (char*)As + (w * 32 + i * 8) * 128);
      gload_lds16(&Wt[(size_t)(col0 + rr) * DIN + k0 + s * 8],
                  (char*)Bs + (w * 32 + i * 8) * 128);
    }
    __syncthreads();  // staging visible
#pragma unroll
    for (int kc = 0; kc < 2; ++kc) {
      bf16x8 a[4], b[4];
#pragma unroll
      for (int mt = 0; mt < 4; ++mt) {
        const int R = wm * 64 + mt * 16 + lc;
        const int ch = (kc * 4 + lg) ^ (R & 7);
        a[mt] = *reinterpret_cast<const bf16x8*>((const char*)As + R * 128 + ch * 16);
      }
#pragma unroll
      for (int nt = 0; nt < 4; ++nt) {
        const int Rn = wn * 64 + nt * 16 + lc;
        const int ch = (kc * 4 + lg) ^ (Rn & 7);
        b[nt] = *reinterpret_cast<const bf16x8*>((const char*)Bs + Rn * 128 + ch * 16);
      }
#pragma unroll
      for (int mt = 0; mt < 4; ++mt)
#pragma unroll
        for (int nt = 0; nt < 4; ++nt)
          acc[mt][nt] = __builtin_amdgcn_mfma_f32_16x16x32_bf16(a[mt], b[nt],
                                                                acc[mt][nt], 0, 0, 0);
    }
  }

  float bv[4];
#pragma unroll
  for (int nt = 0; nt < 4; ++nt) bv[nt] = bin[col0 + wn * 64 + nt * 16 + lc];
#pragma unroll
  for (int mt = 0; mt < 4; ++mt) {
#pragma unroll
    for (int nt = 0; nt < 4; ++nt) {
      const int col = col0 + wn * 64 + nt * 16 + lc;
      const int g = col >> 9;
      const int rem = col & 511;
      const int cgc = rem >> 6, cc = rem & 63;
#pragma unroll
      for (int rr = 0; rr < 4; ++rr) {
        const int m = row0 + wm * 64 + mt * 16 + lg * 4 + rr;
        const int t = m & 63, b = m >> 6;
        const size_t o =
            ((((size_t)t * 16 + (b >> 5)) * 8 + cgc) * 32 + (b & 31)) * 192 +
            g * 64 + cc;
        XG[o] = __float2bfloat16(acc[mt][nt][rr] + bv[nt]);
      }
    }
  }
}

// ---------------------------------------------------------------------------
// Kernel 2: persistent cooperative GRU scan (R15 protocol; final h -> bf16).
// ---------------------------------------------------------------------------
__global__ __launch_bounds__(512, 2) void gru_scan_coop(
    const __hip_bfloat16* __restrict__ XG, const short* __restrict__ Upk2,
    const float* __restrict__ brec, short* h_g, unsigned* bar,
    short* __restrict__ HTb) {
  __shared__ __align__(16) short hS[32 * 512];   // 32 KB (swizzled image)
  __shared__ __align__(16) short xgL[2][6144];   // 24 KB
  const int tid = threadIdx.x, w = tid >> 6, l = tid & 63;
  const int lc = l & 15, lg = l >> 4;
  const int bg = blockIdx.x >> 3, cgi = blockIdx.x & 7;
  const int b0 = bg * 32, c0 = cgi * 64;
  const int wm = w & 1, wn = w >> 1;  // 2 batch-tiles x 4 col-tiles
  unsigned* const flags = bar + bg * 16;

  // ---- U fragments (one-time load; compiler may stream from L2) ----
  bf16x8 ub[3][16];
#pragma unroll
  for (int g = 0; g < 3; ++g)
#pragma unroll
    for (int kc = 0; kc < 16; ++kc)
      ub[g][kc] = *reinterpret_cast<const bf16x8*>(
          Upk2 + ((((size_t)cgi * 48 + g * 16 + kc) * 4 + wn) * 4 + lg) * 128 +
          lc * 8);

  // zero hS: t=0 computes with h=0 (gates read hold from hS at t=0)
  for (int i = tid; i < 4096; i += 512) ((unsigned long long*)hS)[i] = 0ull;

  const short* XGs = (const short*)XG;
  {  // stage xg(t=0): 12KB slice = 768 chunks (512 + 256), linear
    const short* xs = XGs + ((size_t)bg * 8 + cgi) * 6144;
    gload_lds16(xs + tid * 8, (char*)xgL[0] + w * 1024);
    if (tid < 256)
      gload_lds16(xs + (512 + tid) * 8, (char*)xgL[0] + 8192 + w * 1024);
  }

  const int j = c0 + wn * 16 + lc;  // this lane's h/gate column
  const float brz = brec[j], brr = brec[512 + j], brh = brec[1024 + j];
  const int arow = wm * 16 + lc;

  __syncthreads();  // hS + xg(0) ready (compiler drains vmcnt)

  for (int t = 0; t < TSTEPS; ++t) {
    f32x4 za0 = (f32x4){0.f, 0.f, 0.f, 0.f}, za1 = za0, za2 = za0;
    if (t > 0) {
      // ---- wait for all 8 producers of h(t) ----
      for (;;) {
        const unsigned f = __hip_atomic_load(&flags[l & 7], __ATOMIC_RELAXED,
                                             __HIP_MEMORY_SCOPE_AGENT);
        if (__all((int)(f >= (unsigned)t))) break;
        __builtin_amdgcn_s_sleep(1);
      }
      // ---- coalesced h loads (relaxed agent atomics, swizzled image) ----
      const unsigned long long* hsrc = (const unsigned long long*)(
          h_g + ((size_t)(t & 1) * BATCH + b0) * 512);
      unsigned long long v[8];
#pragma unroll
      for (int r = 0; r < 8; ++r)
        v[r] = __hip_atomic_load(hsrc + r * 512 + tid, __ATOMIC_RELAXED,
                                 __HIP_MEMORY_SCOPE_AGENT);
#pragma unroll
      for (int r = 0; r < 8; ++r)
        ((unsigned long long*)hS)[r * 512 + tid] = v[r];
      __syncthreads();  // hS ready

      // ---- hg = h @ U : 48 MFMAs, A from swizzled hS ----
#pragma unroll
      for (int kc = 0; kc < 16; ++kc) {
        const int s = kc * 4 + lg;
        const bf16x8 a = *(const bf16x8*)((const char*)hS + arow * 1024 +
                                          ((s ^ (arow & 7)) << 4));
        za0 = __builtin_amdgcn_mfma_f32_16x16x32_bf16(a, ub[0][kc], za0, 0, 0, 0);
        za1 = __builtin_amdgcn_mfma_f32_16x16x32_bf16(a, ub[1][kc], za1, 0, 0, 0);
        za2 = __builtin_amdgcn_mfma_f32_16x16x32_bf16(a, ub[2][kc], za2, 0, 0, 0);
      }
    }

    // ---- gates in-register; C/D: col=lane&15, row=(lane>>4)*4+reg ----
    const short* xb = xgL[t & 1];
#pragma unroll
    for (int r = 0; r < 4; ++r) {
      const int lb = wm * 16 + lg * 4 + r;
      const float xz = bf2f(xb[lb * 192 + wn * 16 + lc]);
      const float xr = bf2f(xb[lb * 192 + 64 + wn * 16 + lc]);
      const float xh = bf2f(xb[lb * 192 + 128 + wn * 16 + lc]);
      const float z = 1.f / (1.f + __expf(-(xz + za0[r] + brz)));
      const float rg = 1.f / (1.f + __expf(-(xr + za1[r] + brr)));
      const float hc = fmaxf(fmaf(rg, za2[r] + brh, xh), 0.f);
      const int hoff = lb * 1024 + (((j >> 3) ^ (lb & 7)) << 4) + (j & 7) * 2;
      const float hold = bf2f(*(const short*)((const char*)hS + hoff));
      const float hnew = fmaf(z, hold - hc, hc);
      if (t == TSTEPS - 1) {
        HTb[(size_t)(b0 + lb) * HID + j] = f2bf(hnew);
      } else {
        __hip_atomic_store(
            (unsigned short*)((char*)h_g +
                              ((size_t)((t + 1) & 1) * BATCH + b0) * 1024 + hoff),
            (unsigned short)f2bf(hnew), __ATOMIC_RELAXED,
            __HIP_MEMORY_SCOPE_AGENT);
      }
    }
    if (t == TSTEPS - 1) break;

    __syncthreads();  // all waves' h stores drained (vmcnt 0 before barrier)
    if (tid == 0)
      __hip_atomic_store(&flags[cgi], (unsigned)(t + 1), __ATOMIC_RELAXED,
                         __HIP_MEMORY_SCOPE_AGENT);
    {  // stage xg(t+1) while flags propagate: 12KB slice (768 chunks)
      const short* xs = XGs + (((size_t)(t + 1) * 16 + bg) * 8 + cgi) * 6144;
      char* xd = (char*)xgL[(t + 1) & 1];
      gload_lds16(xs + tid * 8, xd + w * 1024);
      if (tid < 256)
        gload_lds16(xs + (512 + tid) * 8, xd + 8192 + w * 1024);
    }
  }
}

// ---------------------------------------------------------------------------
// Kernel 3: OUT = HTb @ W2st^T + b2 via MFMA (M=512, N=512, K=512).
// 16 blocks of 128x128; both operands via global_load_lds.
// ---------------------------------------------------------------------------
__global__ __launch_bounds__(256) void final_mfma(const short* __restrict__ HTb,
                                                  const short* __restrict__ W2st,
                                                  const float* __restrict__ b2,
                                                  float* __restrict__ OUT) {
  __shared__ __align__(16) short As[128 * 64];
  __shared__ __align__(16) short Bs[128 * 64];
  const int tid = threadIdx.x;
  const int w = tid >> 6, l = tid & 63;
  const int lc = l & 15, lg = l >> 4;
  const int row0 = (blockIdx.x >> 2) * 128, col0 = (blockIdx.x & 3) * 128;
  const int wm = w >> 1, wn = w & 1;

  f32x4 acc[4][4];
#pragma unroll
  for (int mt = 0; mt < 4; ++mt)
#pragma unroll
    for (int nt = 0; nt < 4; ++nt) acc[mt][nt] = (f32x4){0.f, 0.f, 0.f, 0.f};

  for (int k0 = 0; k0 < HID; k0 += 64) {
    __syncthreads();
#pragma unroll
    for (int i = 0; i < 4; ++i) {
      const int rr = w * 32 + i * 8 + (l >> 3);
      const int s = (l & 7) ^ (rr & 7);
      gload_lds16(&HTb[(size_t)(row0 + rr) * HID + k0 + s * 8],
                  (char*)As + (w * 32 + i * 8) * 128);
      gload_lds16(&W2st[(size_t)(col0 + rr) * HID + k0 + s * 8],
                  (char*)Bs + (w * 32 + i * 8) * 128);
    }
    __syncthreads();
#pragma unroll
    for (int kc = 0; kc < 2; ++kc) {
      bf16x8 a[4], b[4];
#pragma unroll
      for (int mt = 0; mt < 4; ++mt) {
        const int R = wm * 64 + mt * 16 + lc;
        const int ch = (kc * 4 + lg) ^ (R & 7);
        a[mt] = *reinterpret_cast<const bf16x8*>((const char*)As + R * 128 + ch * 16);
      }
#pragma unroll
      for (int nt = 0; nt < 4; ++nt) {
        const int Rn = wn * 64 + nt * 16 + lc;
        const int ch = (kc * 4 + lg) ^ (Rn & 7);
        b[nt] = *reinterpret_cast<const bf16x8*>((const char*)Bs + Rn * 128 + ch * 16);
      }
#pragma unroll
      for (int mt = 0; mt < 4; ++mt)
#pragma unroll
        for (int nt = 0; nt < 4; ++nt)
          acc[mt][nt] = __builtin_amdgcn_mfma_f32_16x16x32_bf16(a[mt], b[nt],
                                                                acc[mt][nt], 0, 0, 0);
    }
  }

  float bv[4];
#pragma unroll
  for (int nt = 0; nt < 4; ++nt) bv[nt] = b2[col0 + wn * 64 + nt * 16 + lc];
#pragma unroll
  for (int mt = 0; mt < 4; ++mt) {
#pragma unroll
    for (int nt = 0; nt < 4; ++nt) {
      const int col = col0 + wn * 64 + nt * 16 + lc;
#pragma unroll
      for (int rr = 0; rr < 4; ++rr) {
        const int row = row0 + wm * 64 + mt * 16 + lg * 4 + rr;
        OUT[(size_t)row * POUT + col] = acc[mt][nt][rr] + bv[nt];
      }
    }
  }
}

// ---------------------------------------------------------------------------
extern "C" void kernel_launch(void* const* d_in, const int* in_sizes, int n_in,
                              void* d_out, int out_size, void* d_ws,
                              size_t ws_size, hipStream_t stream) {
  const float* X    = (const float*)d_in[0];
  const float* Win  = (const float*)d_in[1];
  const float* bin  = (const float*)d_in[2];
  const float* U    = (const float*)d_in[3];
  const float* brec = (const float*)d_in[4];
  const float* W2   = (const float*)d_in[5];
  const float* b2   = (const float*)d_in[6];
  float* OUT = (float*)d_out;

  char* ws = (char*)d_ws;
  size_t off = 0;
  __hip_bfloat16* XG = (__hip_bfloat16*)(ws + off); off += (size_t)MROWS * G3 * 2;  // 100.66 MB
  short* Wt   = (short*)(ws + off); off += (size_t)G3 * DIN * 2;                    // 3.15 MB
  short* Upk2 = (short*)(ws + off); off += (size_t)G3 * HID * 2;                    // 1.57 MB
  short* HTb  = (short*)(ws + off); off += (size_t)BATCH * HID * 2;                 // 0.52 MB
  short* W2st = (short*)(ws + off); off += (size_t)HID * POUT * 2;                  // 0.52 MB
  short* h_g  = (short*)(ws + off); off += (size_t)2 * BATCH * HID * 2;             // 1.05 MB (dbuf)
  unsigned* bar = (unsigned*)(ws + off); off += 4096;                               // flags
  short* Xbf  = (short*)(ws + off); off += (size_t)MROWS * DIN * 2;                 // 67.1 MB -> ~175 MB

  hipMemsetAsync(bar, 0, 1024, stream);  // flag slots; h_g needs no reset

  xcast<<<(MROWS * DIN) / (256 * 8), 256, 0, stream>>>(X, Xbf);
  transpose_cast<<<dim3(G3 / 32, DIN / 32), 256, 0, stream>>>(Win, Wt, DIN, G3);
  u_pack2<<<(HID * G3) / 256, 256, 0, stream>>>(U, Upk2);
  w2_pack<<<dim3(POUT / 32, HID / 32), 256, 0, stream>>>(W2, W2st);
  gemm_xg_mfma<<<(MROWS / 128) * (G3 / 128), 256, 0, stream>>>(Xbf, Wt, bin, XG);

  const __hip_bfloat16* XGc = XG;
  const short* Upkc = Upk2;
  void* args[] = {(void*)&XGc, (void*)&Upkc, (void*)&brec,
                  (void*)&h_g, (void*)&bar, (void*)&HTb};
  hipLaunchCooperativeKernel((const void*)gru_scan_coop, dim3(128), dim3(512),
                             args, 0, stream);

  final_mfma<<<16, 256, 0, stream>>>(HTb, W2st, b2, OUT);
}